// Round 1
// baseline (517.868 us; speedup 1.0000x reference)
//
#include <hip/hip_runtime.h>
#include <hip/hip_bf16.h>

#define SLEN   2048
#define DMODEL 1024
#define NHEADS 16
#define DHEAD  64
#define NBATCH 2
#define EPAD_ROWS 2176   // SLEN + 128 zero rows so rel-band MFMA never reads OOB

typedef __bf16 bf16x8 __attribute__((ext_vector_type(8)));
typedef float  f32x4  __attribute__((ext_vector_type(4)));

__device__ __forceinline__ unsigned short f2bf(float f) {
    unsigned int u = __builtin_bit_cast(unsigned int, f);
    return (unsigned short)((u + 0x7fffu + ((u >> 16) & 1u)) >> 16);  // RNE
}

__device__ __forceinline__ bf16x8 ld8(const unsigned short* p) {
    union { uint4 u; bf16x8 b; } t;
    t.u = *(const uint4*)p;
    return t.b;
}

// ---------------- prep kernels ----------------

__global__ void cvt_x(const float* __restrict__ x, unsigned short* __restrict__ xb) {
    int i = (blockIdx.x * 256 + threadIdx.x) * 4;
    if (i < NBATCH * SLEN * DMODEL) {
        float4 v = *(const float4*)(x + i);
        ushort4 o;
        o.x = f2bf(v.x); o.y = f2bf(v.y); o.z = f2bf(v.z); o.w = f2bf(v.w);
        *(ushort4*)(xb + i) = o;
    }
}

// W (k,n) fp32 -> Wt[z][n][k] bf16  (B-fragment wants k-contiguous)
__global__ void cvt_wt(const float* __restrict__ Wq, const float* __restrict__ Wk,
                       const float* __restrict__ Wv, unsigned short* __restrict__ Wt) {
    __shared__ float tile[32][33];
    int z = blockIdx.z;
    const float* W = (z == 0) ? Wq : (z == 1 ? Wk : Wv);
    unsigned short* out = Wt + (size_t)z * DMODEL * DMODEL;
    int k0 = blockIdx.y * 32, n0 = blockIdx.x * 32;
    int tx = threadIdx.x, ty = threadIdx.y;  // (32,8)
    for (int r = 0; r < 32; r += 8)
        tile[ty + r][tx] = W[(size_t)(k0 + ty + r) * DMODEL + n0 + tx];
    __syncthreads();
    for (int r = 0; r < 32; r += 8)
        out[(size_t)(n0 + ty + r) * DMODEL + k0 + tx] = f2bf(tile[tx][ty + r]);
}

// Er (2048,64) fp32 -> bf16 padded to EPAD_ROWS (zeros beyond)
__global__ void cvt_er(const float* __restrict__ Er, unsigned short* __restrict__ Ep) {
    int i = blockIdx.x * 256 + threadIdx.x;      // 2176*64 elements
    int row = i >> 6;
    unsigned short v = 0;
    if (row < SLEN) v = f2bf(Er[i]);
    Ep[i] = v;
}

// ---------------- QKV projection GEMM ----------------
// C(4096x1024) = xb(4096x1024) @ W ; per z: Q (pre-scaled 0.125, (BH,S,64)),
// K ((BH,S,64)), V stored transposed ((BH,64,S)).
__global__ __launch_bounds__(256) void qkv_gemm(
    const unsigned short* __restrict__ xb, const unsigned short* __restrict__ Wt,
    const float* __restrict__ bq, const float* __restrict__ bk, const float* __restrict__ bv,
    unsigned short* __restrict__ Qs, unsigned short* __restrict__ Ks,
    unsigned short* __restrict__ Vts) {
    const int z = blockIdx.z;
    const float* bias = (z == 0) ? bq : (z == 1 ? bk : bv);
    const unsigned short* Wz = Wt + (size_t)z * DMODEL * DMODEL;
    const int m0 = blockIdx.y * 64, n0 = blockIdx.x * 64;

    __shared__ __align__(16) unsigned short As[64][80];  // pad to 80 keeps 16B align
    __shared__ __align__(16) unsigned short Bs[64][80];

    const int tid = threadIdx.x;
    const int wave = tid >> 6, lane = tid & 63, l16 = lane & 15, quad = lane >> 4;
    const int lr = tid >> 3, lc = (tid & 7) * 8;

    f32x4 acc[4];
#pragma unroll
    for (int nt = 0; nt < 4; nt++) acc[nt] = (f32x4){0.f, 0.f, 0.f, 0.f};

    for (int k0 = 0; k0 < DMODEL; k0 += 64) {
        *(uint4*)&As[lr][lc]      = *(const uint4*)&xb[(size_t)(m0 + lr) * DMODEL + k0 + lc];
        *(uint4*)&As[lr + 32][lc] = *(const uint4*)&xb[(size_t)(m0 + lr + 32) * DMODEL + k0 + lc];
        *(uint4*)&Bs[lr][lc]      = *(const uint4*)&Wz[(size_t)(n0 + lr) * DMODEL + k0 + lc];
        *(uint4*)&Bs[lr + 32][lc] = *(const uint4*)&Wz[(size_t)(n0 + lr + 32) * DMODEL + k0 + lc];
        __syncthreads();
#pragma unroll
        for (int ks = 0; ks < 2; ks++) {
            bf16x8 a = ld8(&As[wave * 16 + l16][ks * 32 + quad * 8]);
#pragma unroll
            for (int nt = 0; nt < 4; nt++) {
                bf16x8 b = ld8(&Bs[nt * 16 + l16][ks * 32 + quad * 8]);
                acc[nt] = __builtin_amdgcn_mfma_f32_16x16x32_bf16(a, b, acc[nt], 0, 0, 0);
            }
        }
        __syncthreads();
    }

#pragma unroll
    for (int nt = 0; nt < 4; nt++) {
        const int n = n0 + nt * 16 + l16;
        const float bb = bias[n];
        const int h = n >> 6, d = n & 63;
#pragma unroll
        for (int r = 0; r < 4; r++) {
            const int m = m0 + wave * 16 + quad * 4 + r;
            const int bi = m >> 11, s = m & 2047;
            float v = acc[nt][r] + bb;
            if (z == 0)
                Qs[((size_t)(bi * NHEADS + h) * SLEN + s) * 64 + d] = f2bf(v * 0.125f);
            else if (z == 1)
                Ks[((size_t)(bi * NHEADS + h) * SLEN + s) * 64 + d] = f2bf(v);
            else
                Vts[((size_t)(bi * NHEADS + h) * 64 + d) * SLEN + s] = f2bf(v);
        }
    }
}

// ---------------- fused causal flash attention with skewed rel-pos ----------------
// Srel[s,t] = QEr[s, S-1-s+t]  (t<=s). Per wave band: l0w = S-64-s0+t0+48-16*wave,
// gather u = t_local + 15 - row16, u in [0,78] -> 5 n-tiles of 16.
__global__ __launch_bounds__(256) void attn_kernel(
    const unsigned short* __restrict__ Q,   // (BH,S,64), pre-scaled by 0.125
    const unsigned short* __restrict__ K,   // (BH,S,64)
    const unsigned short* __restrict__ Vt,  // (BH,64,S)
    const unsigned short* __restrict__ Ep,  // (EPAD_ROWS,64)
    float* __restrict__ out) {              // (B,S,DMODEL)
    const int i = blockIdx.x;   // s-tile
    const int bh = blockIdx.y;
    const int s0 = i * 64;
    const int tid = threadIdx.x;
    const int wave = tid >> 6, lane = tid & 63, l16 = lane & 15, quad = lane >> 4;

    __shared__ __align__(16) float Eg[4][16][84];            // per-wave QEr band
    __shared__ __align__(16) unsigned short Pg[4][16][80];   // per-wave P (bf16)

    const unsigned short* Qb = Q + (size_t)bh * SLEN * 64;
    const unsigned short* Kb = K + (size_t)bh * SLEN * 64;
    const unsigned short* Vb = Vt + (size_t)bh * 64 * SLEN;

    const int qrow = s0 + wave * 16 + l16;
    const bf16x8 aq0 = ld8(Qb + (size_t)qrow * 64 + quad * 8);
    const bf16x8 aq1 = ld8(Qb + (size_t)qrow * 64 + 32 + quad * 8);

    f32x4 accO[4];
    float mrun[4], lrun[4];
#pragma unroll
    for (int nt = 0; nt < 4; nt++) accO[nt] = (f32x4){0.f, 0.f, 0.f, 0.f};
#pragma unroll
    for (int r = 0; r < 4; r++) { mrun[r] = -__builtin_inff(); lrun[r] = 0.f; }

    for (int j = 0; j <= i; ++j) {
        const int t0 = j * 64;

        // ---- scores: QK^T ----
        f32x4 accS[4];
#pragma unroll
        for (int nt = 0; nt < 4; nt++) accS[nt] = (f32x4){0.f, 0.f, 0.f, 0.f};
#pragma unroll
        for (int nt = 0; nt < 4; nt++) {
            const unsigned short* kp = Kb + (size_t)(t0 + nt * 16 + l16) * 64 + quad * 8;
            bf16x8 b0 = ld8(kp);
            bf16x8 b1 = ld8(kp + 32);
            accS[nt] = __builtin_amdgcn_mfma_f32_16x16x32_bf16(aq0, b0, accS[nt], 0, 0, 0);
            accS[nt] = __builtin_amdgcn_mfma_f32_16x16x32_bf16(aq1, b1, accS[nt], 0, 0, 0);
        }

        // ---- rel band: QEr (80 wide per wave) ----
        const int l0w = (SLEN - 64 - s0 + t0) + 48 - 16 * wave;
        f32x4 accE[5];
#pragma unroll
        for (int nt = 0; nt < 5; nt++) accE[nt] = (f32x4){0.f, 0.f, 0.f, 0.f};
#pragma unroll
        for (int nt = 0; nt < 5; nt++) {
            const unsigned short* ep = Ep + (size_t)(l0w + nt * 16 + l16) * 64 + quad * 8;
            bf16x8 b0 = ld8(ep);
            bf16x8 b1 = ld8(ep + 32);
            accE[nt] = __builtin_amdgcn_mfma_f32_16x16x32_bf16(aq0, b0, accE[nt], 0, 0, 0);
            accE[nt] = __builtin_amdgcn_mfma_f32_16x16x32_bf16(aq1, b1, accE[nt], 0, 0, 0);
        }
#pragma unroll
        for (int nt = 0; nt < 5; nt++)
#pragma unroll
            for (int r = 0; r < 4; r++)
                Eg[wave][quad * 4 + r][nt * 16 + l16] = accE[nt][r];
        __syncthreads();

        // ---- gather rel + causal mask ----
        float vals[4][4];
#pragma unroll
        for (int nt = 0; nt < 4; nt++) {
            const int t = t0 + nt * 16 + l16;
#pragma unroll
            for (int r = 0; r < 4; r++) {
                const int row16 = quad * 4 + r;
                const int s = s0 + wave * 16 + row16;
                float v = accS[nt][r] + Eg[wave][row16][nt * 16 + l16 + 15 - row16];
                vals[nt][r] = (t <= s) ? v : -__builtin_inff();
            }
        }

        // ---- online softmax (rows live in 16-lane quad groups) ----
        float alpha[4];
#pragma unroll
        for (int r = 0; r < 4; r++) {
            float v = fmaxf(fmaxf(vals[0][r], vals[1][r]), fmaxf(vals[2][r], vals[3][r]));
#pragma unroll
            for (int off = 1; off < 16; off <<= 1) v = fmaxf(v, __shfl_xor(v, off));
            float mnew = fmaxf(mrun[r], v);
            alpha[r] = __expf(mrun[r] - mnew);
            mrun[r] = mnew;
        }
#pragma unroll
        for (int nt = 0; nt < 4; nt++)
#pragma unroll
            for (int r = 0; r < 4; r++)
                vals[nt][r] = __expf(vals[nt][r] - mrun[r]);
#pragma unroll
        for (int r = 0; r < 4; r++) {
            float s4 = (vals[0][r] + vals[1][r]) + (vals[2][r] + vals[3][r]);
#pragma unroll
            for (int off = 1; off < 16; off <<= 1) s4 += __shfl_xor(s4, off);
            lrun[r] = lrun[r] * alpha[r] + s4;
        }
#pragma unroll
        for (int nt = 0; nt < 4; nt++)
#pragma unroll
            for (int r = 0; r < 4; r++) accO[nt][r] *= alpha[r];

        // ---- P -> LDS (C-layout -> A-layout round trip) ----
#pragma unroll
        for (int nt = 0; nt < 4; nt++)
#pragma unroll
            for (int r = 0; r < 4; r++)
                Pg[wave][quad * 4 + r][nt * 16 + l16] = f2bf(vals[nt][r]);
        __syncthreads();

        // ---- PV ----
        bf16x8 a0 = ld8(&Pg[wave][l16][quad * 8]);
        bf16x8 a1 = ld8(&Pg[wave][l16][32 + quad * 8]);
#pragma unroll
        for (int nt = 0; nt < 4; nt++) {
            const unsigned short* vp = Vb + (size_t)(nt * 16 + l16) * SLEN + t0 + quad * 8;
            bf16x8 b0 = ld8(vp);
            bf16x8 b1 = ld8(vp + 32);
            accO[nt] = __builtin_amdgcn_mfma_f32_16x16x32_bf16(a0, b0, accO[nt], 0, 0, 0);
            accO[nt] = __builtin_amdgcn_mfma_f32_16x16x32_bf16(a1, b1, accO[nt], 0, 0, 0);
        }
    }

    // ---- epilogue: normalize + store fp32 ----
    const int b = bh >> 4, h = bh & 15;
#pragma unroll
    for (int r = 0; r < 4; r++) {
        const float inv = 1.f / lrun[r];
        const int s = s0 + wave * 16 + quad * 4 + r;
#pragma unroll
        for (int nt = 0; nt < 4; nt++)
            out[((size_t)(b * SLEN + s)) * DMODEL + h * 64 + nt * 16 + l16] = accO[nt][r] * inv;
    }
}

// ---------------- host launcher ----------------
extern "C" void kernel_launch(void* const* d_in, const int* in_sizes, int n_in,
                              void* d_out, int out_size, void* d_ws, size_t ws_size,
                              hipStream_t stream) {
    const float* x  = (const float*)d_in[0];
    const float* Wq = (const float*)d_in[1];
    const float* bq = (const float*)d_in[2];
    const float* Wk = (const float*)d_in[3];
    const float* bk = (const float*)d_in[4];
    const float* Wv = (const float*)d_in[5];
    const float* bv = (const float*)d_in[6];
    const float* Er = (const float*)d_in[7];
    float* out = (float*)d_out;

    // workspace carve (~38.3 MB total)
    char* p = (char*)d_ws;
    unsigned short* xb  = (unsigned short*)p; p += (size_t)4096 * 1024 * 2;
    unsigned short* Wt  = (unsigned short*)p; p += (size_t)3 * 1024 * 1024 * 2;
    unsigned short* Qs  = (unsigned short*)p; p += (size_t)32 * 2048 * 64 * 2;
    unsigned short* Ks  = (unsigned short*)p; p += (size_t)32 * 2048 * 64 * 2;
    unsigned short* Vts = (unsigned short*)p; p += (size_t)32 * 2048 * 64 * 2;
    unsigned short* Ep  = (unsigned short*)p; p += (size_t)EPAD_ROWS * 64 * 2;

    hipLaunchKernelGGL(cvt_x, dim3(4096), dim3(256), 0, stream, x, xb);
    hipLaunchKernelGGL(cvt_wt, dim3(32, 32, 3), dim3(32, 8), 0, stream, Wq, Wk, Wv, Wt);
    hipLaunchKernelGGL(cvt_er, dim3(544), dim3(256), 0, stream, Er, Ep);
    hipLaunchKernelGGL(qkv_gemm, dim3(16, 64, 3), dim3(256), 0, stream,
                       xb, Wt, bq, bk, bv, Qs, Ks, Vts);
    hipLaunchKernelGGL(attn_kernel, dim3(32, 32), dim3(256), 0, stream, Qs, Ks, Vts, Ep, out);
}

// Round 2
// 360.049 us; speedup vs baseline: 1.4383x; 1.4383x over previous
//
#include <hip/hip_runtime.h>
#include <hip/hip_bf16.h>

#define SLEN   2048
#define DMODEL 1024
#define NHEADS 16
#define DHEAD  64
#define NBATCH 2
#define EPAD_ROWS 2176   // SLEN + 128 zero rows so rel-band MFMA never reads OOB

typedef __bf16 bf16x8 __attribute__((ext_vector_type(8)));
typedef float  f32x4  __attribute__((ext_vector_type(4)));

__device__ __forceinline__ unsigned short f2bf(float f) {
    unsigned int u = __builtin_bit_cast(unsigned int, f);
    return (unsigned short)((u + 0x7fffu + ((u >> 16) & 1u)) >> 16);  // RNE
}

__device__ __forceinline__ bf16x8 ld8(const unsigned short* p) {
    union { uint4 u; bf16x8 b; } t;
    t.u = *(const uint4*)p;
    return t.b;
}

// ---------------- prep kernels ----------------

__global__ void cvt_x(const float* __restrict__ x, unsigned short* __restrict__ xb) {
    int i = (blockIdx.x * 256 + threadIdx.x) * 4;
    if (i < NBATCH * SLEN * DMODEL) {
        float4 v = *(const float4*)(x + i);
        ushort4 o;
        o.x = f2bf(v.x); o.y = f2bf(v.y); o.z = f2bf(v.z); o.w = f2bf(v.w);
        *(ushort4*)(xb + i) = o;
    }
}

// W (k,n) fp32 -> Wt[z][n][k] bf16  (B-fragment wants k-contiguous)
__global__ void cvt_wt(const float* __restrict__ Wq, const float* __restrict__ Wk,
                       const float* __restrict__ Wv, unsigned short* __restrict__ Wt) {
    __shared__ float tile[32][33];
    int z = blockIdx.z;
    const float* W = (z == 0) ? Wq : (z == 1 ? Wk : Wv);
    unsigned short* out = Wt + (size_t)z * DMODEL * DMODEL;
    int k0 = blockIdx.y * 32, n0 = blockIdx.x * 32;
    int tx = threadIdx.x, ty = threadIdx.y;  // (32,8)
    for (int r = 0; r < 32; r += 8)
        tile[ty + r][tx] = W[(size_t)(k0 + ty + r) * DMODEL + n0 + tx];
    __syncthreads();
    for (int r = 0; r < 32; r += 8)
        out[(size_t)(n0 + ty + r) * DMODEL + k0 + tx] = f2bf(tile[tx][ty + r]);
}

// Er (2048,64) fp32 -> bf16 padded to EPAD_ROWS (zeros beyond)
__global__ void cvt_er(const float* __restrict__ Er, unsigned short* __restrict__ Ep) {
    int i = blockIdx.x * 256 + threadIdx.x;      // 2176*64 elements
    int row = i >> 6;
    unsigned short v = 0;
    if (row < SLEN) v = f2bf(Er[i]);
    Ep[i] = v;
}

// ---------------- QKV projection GEMM (128x128 tile, 4 waves x 64x64) -------
// C(4096x1024) = xb(4096x1024) @ W ; per z: Q (pre-scaled 0.125, (BH,S,64)),
// K ((BH,S,64)), V stored transposed ((BH,64,S)).
__global__ __launch_bounds__(256) void qkv_gemm(
    const unsigned short* __restrict__ xb, const unsigned short* __restrict__ Wt,
    const float* __restrict__ bq, const float* __restrict__ bk, const float* __restrict__ bv,
    unsigned short* __restrict__ Qs, unsigned short* __restrict__ Ks,
    unsigned short* __restrict__ Vts) {
    const int z = blockIdx.z;
    const float* bias = (z == 0) ? bq : (z == 1 ? bk : bv);
    const unsigned short* Wz = Wt + (size_t)z * DMODEL * DMODEL;
    const int m0 = blockIdx.y * 128, n0 = blockIdx.x * 128;

    __shared__ __align__(16) unsigned short As[128][72];  // pad 72: 2-way (free) banks
    __shared__ __align__(16) unsigned short Bs[128][72];

    const int tid = threadIdx.x;
    const int wave = tid >> 6, lane = tid & 63, l16 = lane & 15, quad = lane >> 4;
    const int wm = (wave >> 1) * 64, wn = (wave & 1) * 64;
    const int lr = tid >> 3, lc = (tid & 7) * 8;

    f32x4 acc[4][4];
#pragma unroll
    for (int mi = 0; mi < 4; mi++)
#pragma unroll
        for (int ni = 0; ni < 4; ni++) acc[mi][ni] = (f32x4){0.f, 0.f, 0.f, 0.f};

    for (int k0 = 0; k0 < DMODEL; k0 += 64) {
#pragma unroll
        for (int i = 0; i < 4; i++) {
            *(uint4*)&As[lr + i * 32][lc] =
                *(const uint4*)&xb[(size_t)(m0 + lr + i * 32) * DMODEL + k0 + lc];
            *(uint4*)&Bs[lr + i * 32][lc] =
                *(const uint4*)&Wz[(size_t)(n0 + lr + i * 32) * DMODEL + k0 + lc];
        }
        __syncthreads();
#pragma unroll
        for (int ks = 0; ks < 2; ks++) {
            bf16x8 a[4], b[4];
#pragma unroll
            for (int mi = 0; mi < 4; mi++) a[mi] = ld8(&As[wm + mi * 16 + l16][ks * 32 + quad * 8]);
#pragma unroll
            for (int ni = 0; ni < 4; ni++) b[ni] = ld8(&Bs[wn + ni * 16 + l16][ks * 32 + quad * 8]);
#pragma unroll
            for (int mi = 0; mi < 4; mi++)
#pragma unroll
                for (int ni = 0; ni < 4; ni++)
                    acc[mi][ni] = __builtin_amdgcn_mfma_f32_16x16x32_bf16(a[mi], b[ni], acc[mi][ni], 0, 0, 0);
        }
        __syncthreads();
    }

#pragma unroll
    for (int ni = 0; ni < 4; ni++) {
        const int n = n0 + wn + ni * 16 + l16;
        const float bb = bias[n];
        const int h = n >> 6, d = n & 63;
#pragma unroll
        for (int mi = 0; mi < 4; mi++)
#pragma unroll
            for (int r = 0; r < 4; r++) {
                const int m = m0 + wm + mi * 16 + quad * 4 + r;
                const int bi = m >> 11, s = m & 2047;
                float v = acc[mi][ni][r] + bb;
                if (z == 0)
                    Qs[((size_t)(bi * NHEADS + h) * SLEN + s) * 64 + d] = f2bf(v * 0.125f);
                else if (z == 1)
                    Ks[((size_t)(bi * NHEADS + h) * SLEN + s) * 64 + d] = f2bf(v);
                else
                    Vts[((size_t)(bi * NHEADS + h) * 64 + d) * SLEN + s] = f2bf(v);
            }
    }
}

// ---------------- fused causal flash attention with skewed rel-pos ----------
// Fully wave-independent: each wave owns a 16-row q-tile; NO barriers.
// Srel[s,t] = QEr[s, S-1-s+t]. Band start l0 = S-16-s0+t0; gather
// u = nt*16 + l16 + 15 - row16 in [0,78].
__global__ __launch_bounds__(256) void attn_kernel(
    const unsigned short* __restrict__ Q,   // (BH,S,64), pre-scaled by 0.125
    const unsigned short* __restrict__ K,   // (BH,S,64)
    const unsigned short* __restrict__ Vt,  // (BH,64,S)
    const unsigned short* __restrict__ Ep,  // (EPAD_ROWS,64)
    float* __restrict__ out) {              // (B,S,DMODEL)
    const int tid = threadIdx.x;
    const int wave = tid >> 6, lane = tid & 63, l16 = lane & 15, quad = lane >> 4;

    const int bh  = blockIdx.x & 31;           // fast-varying: spreads long blocks
    const int grp = 31 - (blockIdx.x >> 5);    // longest tasks at low blockIdx
    const int qt  = grp * 4 + wave;            // q-tile (16 rows), same trips per wave
    const int s0  = qt * 16;
    const int jmax = qt >> 2;                  // == grp

    __shared__ __align__(16) float Eg[4][16][84];            // per-wave QEr band
    __shared__ __align__(16) unsigned short Pg[4][16][80];   // per-wave P (bf16)

    const unsigned short* Qb = Q + (size_t)bh * SLEN * 64;
    const unsigned short* Kb = K + (size_t)bh * SLEN * 64;
    const unsigned short* Vb = Vt + (size_t)bh * 64 * SLEN;

    const int qrow = s0 + l16;
    const bf16x8 aq0 = ld8(Qb + (size_t)qrow * 64 + quad * 8);
    const bf16x8 aq1 = ld8(Qb + (size_t)qrow * 64 + 32 + quad * 8);

    f32x4 accO[4];
    float mrun[4], lrun[4];
#pragma unroll
    for (int nt = 0; nt < 4; nt++) accO[nt] = (f32x4){0.f, 0.f, 0.f, 0.f};
#pragma unroll
    for (int r = 0; r < 4; r++) { mrun[r] = -__builtin_inff(); lrun[r] = 0.f; }

    for (int j = 0; j <= jmax; ++j) {
        const int t0 = j * 64;

        // ---- rel band: QEr (80 wide) ----
        const int l0 = SLEN - 16 - s0 + t0;
        f32x4 accE[5];
#pragma unroll
        for (int nt = 0; nt < 5; nt++) accE[nt] = (f32x4){0.f, 0.f, 0.f, 0.f};
#pragma unroll
        for (int nt = 0; nt < 5; nt++) {
            const unsigned short* ep = Ep + (size_t)(l0 + nt * 16 + l16) * 64 + quad * 8;
            bf16x8 b0 = ld8(ep);
            bf16x8 b1 = ld8(ep + 32);
            accE[nt] = __builtin_amdgcn_mfma_f32_16x16x32_bf16(aq0, b0, accE[nt], 0, 0, 0);
            accE[nt] = __builtin_amdgcn_mfma_f32_16x16x32_bf16(aq1, b1, accE[nt], 0, 0, 0);
        }
#pragma unroll
        for (int nt = 0; nt < 5; nt++)
#pragma unroll
            for (int r = 0; r < 4; r++)
                Eg[wave][quad * 4 + r][nt * 16 + l16] = accE[nt][r];

        // ---- scores: QK^T ----
        f32x4 accS[4];
#pragma unroll
        for (int nt = 0; nt < 4; nt++) accS[nt] = (f32x4){0.f, 0.f, 0.f, 0.f};
#pragma unroll
        for (int nt = 0; nt < 4; nt++) {
            const unsigned short* kp = Kb + (size_t)(t0 + nt * 16 + l16) * 64 + quad * 8;
            bf16x8 b0 = ld8(kp);
            bf16x8 b1 = ld8(kp + 32);
            accS[nt] = __builtin_amdgcn_mfma_f32_16x16x32_bf16(aq0, b0, accS[nt], 0, 0, 0);
            accS[nt] = __builtin_amdgcn_mfma_f32_16x16x32_bf16(aq1, b1, accS[nt], 0, 0, 0);
        }

        // ---- gather rel + causal mask ----
        float vals[4][4];
#pragma unroll
        for (int nt = 0; nt < 4; nt++) {
            const int t = t0 + nt * 16 + l16;
#pragma unroll
            for (int r = 0; r < 4; r++) {
                const int row16 = quad * 4 + r;
                const int s = s0 + row16;
                float v = accS[nt][r] + Eg[wave][row16][nt * 16 + l16 + 15 - row16];
                vals[nt][r] = (t <= s) ? v : -__builtin_inff();
            }
        }

        // ---- online softmax (rows live in 16-lane quad groups) ----
        float alpha[4];
#pragma unroll
        for (int r = 0; r < 4; r++) {
            float v = fmaxf(fmaxf(vals[0][r], vals[1][r]), fmaxf(vals[2][r], vals[3][r]));
#pragma unroll
            for (int off = 1; off < 16; off <<= 1) v = fmaxf(v, __shfl_xor(v, off));
            float mnew = fmaxf(mrun[r], v);
            alpha[r] = __expf(mrun[r] - mnew);
            mrun[r] = mnew;
        }
#pragma unroll
        for (int nt = 0; nt < 4; nt++)
#pragma unroll
            for (int r = 0; r < 4; r++)
                vals[nt][r] = __expf(vals[nt][r] - mrun[r]);
#pragma unroll
        for (int r = 0; r < 4; r++) {
            float s4 = (vals[0][r] + vals[1][r]) + (vals[2][r] + vals[3][r]);
#pragma unroll
            for (int off = 1; off < 16; off <<= 1) s4 += __shfl_xor(s4, off);
            lrun[r] = lrun[r] * alpha[r] + s4;
        }
#pragma unroll
        for (int nt = 0; nt < 4; nt++)
#pragma unroll
            for (int r = 0; r < 4; r++) accO[nt][r] *= alpha[r];

        // ---- P -> LDS (C-layout -> A-layout round trip, same wave only) ----
#pragma unroll
        for (int nt = 0; nt < 4; nt++)
#pragma unroll
            for (int r = 0; r < 4; r++)
                Pg[wave][quad * 4 + r][nt * 16 + l16] = f2bf(vals[nt][r]);

        // ---- PV ----
        bf16x8 a0 = ld8(&Pg[wave][l16][quad * 8]);
        bf16x8 a1 = ld8(&Pg[wave][l16][32 + quad * 8]);
#pragma unroll
        for (int nt = 0; nt < 4; nt++) {
            const unsigned short* vp = Vb + (size_t)(nt * 16 + l16) * SLEN + t0 + quad * 8;
            bf16x8 b0 = ld8(vp);
            bf16x8 b1 = ld8(vp + 32);
            accO[nt] = __builtin_amdgcn_mfma_f32_16x16x32_bf16(a0, b0, accO[nt], 0, 0, 0);
            accO[nt] = __builtin_amdgcn_mfma_f32_16x16x32_bf16(a1, b1, accO[nt], 0, 0, 0);
        }
    }

    // ---- epilogue: normalize + store fp32 ----
    const int b = bh >> 4, h = bh & 15;
#pragma unroll
    for (int r = 0; r < 4; r++) {
        const float inv = 1.f / lrun[r];
        const int s = s0 + quad * 4 + r;
#pragma unroll
        for (int nt = 0; nt < 4; nt++)
            out[((size_t)(b * SLEN + s)) * DMODEL + h * 64 + nt * 16 + l16] = accO[nt][r] * inv;
    }
}

// ---------------- host launcher ----------------
extern "C" void kernel_launch(void* const* d_in, const int* in_sizes, int n_in,
                              void* d_out, int out_size, void* d_ws, size_t ws_size,
                              hipStream_t stream) {
    const float* x  = (const float*)d_in[0];
    const float* Wq = (const float*)d_in[1];
    const float* bq = (const float*)d_in[2];
    const float* Wk = (const float*)d_in[3];
    const float* bk = (const float*)d_in[4];
    const float* Wv = (const float*)d_in[5];
    const float* bv = (const float*)d_in[6];
    const float* Er = (const float*)d_in[7];
    float* out = (float*)d_out;

    // workspace carve (~38.3 MB total)
    char* p = (char*)d_ws;
    unsigned short* xb  = (unsigned short*)p; p += (size_t)4096 * 1024 * 2;
    unsigned short* Wt  = (unsigned short*)p; p += (size_t)3 * 1024 * 1024 * 2;
    unsigned short* Qs  = (unsigned short*)p; p += (size_t)32 * 2048 * 64 * 2;
    unsigned short* Ks  = (unsigned short*)p; p += (size_t)32 * 2048 * 64 * 2;
    unsigned short* Vts = (unsigned short*)p; p += (size_t)32 * 2048 * 64 * 2;
    unsigned short* Ep  = (unsigned short*)p; p += (size_t)EPAD_ROWS * 64 * 2;

    hipLaunchKernelGGL(cvt_x, dim3(4096), dim3(256), 0, stream, x, xb);
    hipLaunchKernelGGL(cvt_wt, dim3(32, 32, 3), dim3(32, 8), 0, stream, Wq, Wk, Wv, Wt);
    hipLaunchKernelGGL(cvt_er, dim3(544), dim3(256), 0, stream, Er, Ep);
    hipLaunchKernelGGL(qkv_gemm, dim3(8, 32, 3), dim3(256), 0, stream,
                       xb, Wt, bq, bk, bv, Qs, Ks, Vts);
    hipLaunchKernelGGL(attn_kernel, dim3(1024), dim3(256), 0, stream, Qs, Ks, Vts, Ep, out);
}